// Round 13
// baseline (97.155 us; speedup 1.0000x reference)
//
#include <hip/hip_runtime.h>
#include <hip/hip_bf16.h>
#include <math.h>

// ---------------------------------------------------------------------------
// MMD loss:  mmd = 2*Sxx_upper/(n(n-1)) + 2*Syy_upper/(m(m-1)) - 2*Sxy/(n*m)
// k(a,b) = exp(-|a-b|^2 / 128)  (sigma^2 = D = 64), N = M = 8192, D = 64.
//
// Algebra: store A' = A * sqrt(log2e)/8 in bf16 and ns = -0.5*|a'|^2 (f32,
// NEGATED in prep). Then k = exp2( dot(a',b') + ns_a ) * exp2( ns_b ).
// MFMA C-operand = ns_a (16 regs, C/D row order); ey = exp2(ns_b) once per
// 32x32 tile; per element just exp2 + fma.
//
// Hard-won structure lessons (R0..R12):
//  - default __launch_bounds__(256) ONLY. (256,8) -> compiler spills (373us).
//  - NO single-address atomic finalize (~65us serialized tail, R1/R4).
//  - Guards ARE the register-pressure governor (R1: 108 VGPR, R10: 124).
//  - B panel in LDS, XOR-swizzle f(x)=x^(((x>>7)&7)<<4) BOTH sides (R7).
//  - TLP beyond ~2.5 blocks/CU neutral (R8); 1-deep ds prefetch negative
//    via VGPR cliff at 64 (R11).
//  - R12: 32x32x16 MFMA + multiplicative ey fold: main ~42 -> ~36us.
//  - R13: amortize the survivors. Panel 256 j-cols (32KB LDS): block count
//    2112 -> 1056, A-fragment L2 traffic 135 -> 67MB, per-block overhead
//    halves, A-chunk amortizes over 8 j-tiles. LDS caps 4 blocks/CU
//    (neutral per R8).
// ---------------------------------------------------------------------------

using short8  = __attribute__((ext_vector_type(8))) short;   // 8 bf16
using f32x4   = __attribute__((ext_vector_type(4))) float;
using f32x16  = __attribute__((ext_vector_type(16))) float;
using float4v = __attribute__((ext_vector_type(4))) float;

#define NROWS 8192
#define DDIM  64
// 512 XY (dispatched first) + 2*272 sym-upper (512x256 blocks).
#define GRID_MAIN (512 + 2 * 272)

// sqrt(log2(e)) / 8
#define PRESCALE 0.15014030109830622f

__device__ __forceinline__ float exp2_fast(float x) {
#if __has_builtin(__builtin_amdgcn_exp2f)
    return __builtin_amdgcn_exp2f(x);
#else
    return exp2f(x);
#endif
}

// ---------------------------------------------------------------------------
// Prep: normalize X, prescale, cast X/Y to bf16, compute ns = -0.5*|row'|^2
// (NEGATED: used directly as MFMA C-init / exp2 argument in main).
// 4 rows per wave, float4 loads. (R6-proven.)
// ---------------------------------------------------------------------------
__global__ __launch_bounds__(256) void mmd_prep(
    const float* __restrict__ z_seq, const float* __restrict__ pmean,
    const float* __restrict__ pstd, const float* __restrict__ z_prior,
    __hip_bfloat16* __restrict__ Xb, __hip_bfloat16* __restrict__ Yb,
    float* __restrict__ sxx, float* __restrict__ syy)
{
    const int tid  = threadIdx.x;
    const int lane = tid & 63;
    const int wid  = tid >> 6;
    const int w    = blockIdx.x * 4 + wid;       // wave id, 0..4095
    const int sub  = lane >> 4;                  // row within wave, 0..3
    const int row  = w * 4 + sub;                // 0..16383
    const int d0   = (lane & 15) * 4;            // dim offset, 0..60

    float4v v;
    __hip_bfloat16* dst;
    float* sdst;
    int r;
    if (row < NROWS) {
        r = row;
        float4v z  = *reinterpret_cast<const float4v*>(z_seq + (size_t)r * DDIM + d0);
        float4v pm = *reinterpret_cast<const float4v*>(pmean + d0);
        float4v ps = *reinterpret_cast<const float4v*>(pstd + d0);
#pragma unroll
        for (int k = 0; k < 4; ++k) v[k] = (z[k] - pm[k]) / ps[k];
        dst = Xb; sdst = sxx;
    } else {
        r = row - NROWS;
        v = *reinterpret_cast<const float4v*>(z_prior + (size_t)r * DDIM + d0);
        dst = Yb; sdst = syy;
    }

    ushort4 hb;
    float sq = 0.0f;
#pragma unroll
    for (int k = 0; k < 4; ++k) {
        __hip_bfloat16 b = __float2bfloat16(v[k] * PRESCALE);
        reinterpret_cast<__hip_bfloat16*>(&hb)[k] = b;
        float vb = __bfloat162float(b);
        sq += vb * vb;
    }
    *reinterpret_cast<ushort4*>(dst + (size_t)r * DDIM + d0) = hb;

    // reduce across the 16 lanes of this row-group (xor<16 stays in group)
#pragma unroll
    for (int off = 8; off; off >>= 1) sq += __shfl_xor(sq, off, 64);
    if ((lane & 15) == 0) sdst[r] = -0.5f * sq;   // NEGATED
}

// ---------------------------------------------------------------------------
// Main: compact 1-D grid of ACTIVE blocks only.
// Block tile 512(i) x 256(j): B panel (256x64 bf16 = 32KB) staged once,
// 4 A-chunks of 128 rows swept. 4 waves; per chunk each wave owns 32 rows
// x 8 j-subtiles of 32x32 (v_mfma_f32_32x32x16_bf16, K=16 x4 = K64).
//   bid <  512 : XY block, bi = bid>>5 (0..15), bj = bid&31.
//   bid >= 512 : t = bid-512; sym mode = t&1 (0:XX, 1:YY);
//                u = t>>1 in [0,272): bi has nj = 32-2bi blocks starting at
//                cum(bi)=bi*(33-bi); bj = 2bi + (u-cum).
// 32x32 C/D layout: col = lane&31, row = (reg&3) + 8*(reg>>2) + 4*(lane>>5).
// A/B operand: row/col = lane&31, k = 8*(lane>>5) + elem(0..7).
// ---------------------------------------------------------------------------
__global__ __launch_bounds__(256) void mmd_main(
    const __hip_bfloat16* __restrict__ Xb, const __hip_bfloat16* __restrict__ Yb,
    const float* __restrict__ sxx, const float* __restrict__ syy,
    double* __restrict__ partials)
{
    __shared__ __align__(16) char Bs[32768];     // 256 cols x 128 B

    const int bid = blockIdx.x;

    int bi, bj;
    bool sym;
    const __hip_bfloat16* A;
    const __hip_bfloat16* Bp;
    const float* sa;
    const float* sb;

    if (bid < 512) {                        // XY: heavy, uniform, FIRST
        sym = false;
        bi = bid >> 5; bj = bid & 31;
        A = Xb; Bp = Yb; sa = sxx; sb = syy;
    } else {                                // sym upper-triangle blocks
        sym = true;
        const int t = bid - 512;
        const int u = t >> 1;
        int b = (int)((33.0f - sqrtf(1089.0f - 4.0f * (float)u)) * 0.5f);
        while (b * (33 - b) > u) --b;                  // integer fixup
        while ((b + 1) * (33 - (b + 1)) <= u) ++b;
        bi = b;
        bj = 2 * b + (u - b * (33 - b));    // 2bi .. 31  (jB+256 > iB)
        if (t & 1) { A = Yb; Bp = Yb; sa = syy; sb = syy; }
        else       { A = Xb; Bp = Xb; sa = sxx; sb = sxx; }
    }

    const int tid  = threadIdx.x;
    const int lane = tid & 63;
    const int wid  = tid >> 6;
    const int l31  = lane & 31;
    const int h    = lane >> 5;                  // 0/1: k-half

    const int iBlock = bi * 512;
    const int jBlock = bj * 256;

    // ---- Stage B panel -> LDS, source pre-swizzled with f(x)=x^(((x>>7)&7)<<4)
    // so a swizzled read is conflict-free.  32 chunks of 1024B, 8 per wave.
    {
        const char* gB = (const char*)Bp + (size_t)jBlock * 128;
#pragma unroll
        for (int k = 0; k < 8; ++k) {
            const int c  = wid * 8 + k;
            const int x  = c * 1024 + lane * 16;
            const int gx = x ^ (((x >> 7) & 7) << 4);
            __builtin_amdgcn_global_load_lds(
                (const __attribute__((address_space(1))) void*)(gB + gx),
                (__attribute__((address_space(3))) void*)(Bs + c * 1024),
                16, 0, 0);
        }
    }

    // A-chunk 0 wave row origin; chunk c adds 128.
    int i0 = iBlock + wid * 32;

    // A fragments (4 k-slices) + C-init (negated row half-norms in C/D
    // register order: reg r <- rows 8*(r>>2) + 4h + (r&3)).
    short8 af0, af1, af2, af3;
    f32x16 cin;
    {
        const char* arow = (const char*)A + (size_t)(i0 + l31) * 128 + 16 * h;
        af0 = *reinterpret_cast<const short8*>(arow);
        af1 = *reinterpret_cast<const short8*>(arow + 32);
        af2 = *reinterpret_cast<const short8*>(arow + 64);
        af3 = *reinterpret_cast<const short8*>(arow + 96);
        const float* sna = sa + i0 + 4 * h;
#pragma unroll
        for (int q = 0; q < 4; ++q) {
            f32x4 t = *reinterpret_cast<const f32x4*>(sna + 8 * q);
            cin[4 * q + 0] = t[0]; cin[4 * q + 1] = t[1];
            cin[4 * q + 2] = t[2]; cin[4 * q + 3] = t[3];
        }
    }

    // Negated column half-norms for this lane's 8 j-subtiles.
    float nsy8[8];
#pragma unroll
    for (int nt = 0; nt < 8; ++nt) nsy8[nt] = sb[jBlock + nt * 32 + l31];

    __syncthreads();   // staging complete (compiler drains vmcnt first)

    // Per-lane constant swizzle for reads: col&7 == l31&7 (col = 32nt+l31).
    const int swz = (l31 & 7) << 4;
    const int bo0 = (16 * h +  0) ^ swz;
    const int bo1 = (16 * h + 32) ^ swz;
    const int bo2 = (16 * h + 64) ^ swz;
    const int bo3 = (16 * h + 96) ^ swz;
    const char* lbbase = Bs + l31 * 128;

    // 4 accumulators break the serial add chain.
    float ls0 = 0.0f, ls1 = 0.0f, ls2 = 0.0f, ls3 = 0.0f;

    for (int c = 0; c < 4; ++c) {
#pragma unroll
        for (int nt = 0; nt < 8; ++nt) {
            const int jt = jBlock + nt * 32;
            if (sym && jt < i0) continue;        // tile strictly below diag

            const char* lp = lbbase + nt * 4096;
            short8 b0 = *reinterpret_cast<const short8*>(lp + bo0);
            short8 b1 = *reinterpret_cast<const short8*>(lp + bo1);
            short8 b2 = *reinterpret_cast<const short8*>(lp + bo2);
            short8 b3 = *reinterpret_cast<const short8*>(lp + bo3);

            f32x16 acc = __builtin_amdgcn_mfma_f32_32x32x16_bf16(af0, b0, cin, 0, 0, 0);
            acc = __builtin_amdgcn_mfma_f32_32x32x16_bf16(af1, b1, acc, 0, 0, 0);
            acc = __builtin_amdgcn_mfma_f32_32x32x16_bf16(af2, b2, acc, 0, 0, 0);
            acc = __builtin_amdgcn_mfma_f32_32x32x16_bf16(af3, b3, acc, 0, 0, 0);

            const float ey = exp2_fast(nsy8[nt]);   // exp2(-s_b), once/tile

            if (sym && jt == i0) {
                // diagonal tile: count only j > i; row_r = (r&3)+8*(r>>2)+4h
                const int rb = 4 * h;
#pragma unroll
                for (int r = 0; r < 16; ++r) {
                    const int rowr = rb + (r & 3) + 8 * (r >> 2);
                    float v = exp2_fast(acc[r]) * ey;
                    float m = (l31 > rowr) ? v : 0.0f;
                    if ((r & 3) == 0) ls0 += m;
                    else if ((r & 3) == 1) ls1 += m;
                    else if ((r & 3) == 2) ls2 += m;
                    else ls3 += m;
                }
            } else {
#pragma unroll
                for (int r = 0; r < 16; ++r) {
                    float e = exp2_fast(acc[r]);
                    if ((r & 3) == 0) ls0 = fmaf(e, ey, ls0);
                    else if ((r & 3) == 1) ls1 = fmaf(e, ey, ls1);
                    else if ((r & 3) == 2) ls2 = fmaf(e, ey, ls2);
                    else ls3 = fmaf(e, ey, ls3);
                }
            }
        }

        // Load next chunk's A fragments + C-init.
        if (c < 3) {
            const int i0n = i0 + 128;
            if (sym && jBlock + 224 < i0n) break;   // all later tiles empty
            const char* arow = (const char*)A + (size_t)(i0n + l31) * 128 + 16 * h;
            af0 = *reinterpret_cast<const short8*>(arow);
            af1 = *reinterpret_cast<const short8*>(arow + 32);
            af2 = *reinterpret_cast<const short8*>(arow + 64);
            af3 = *reinterpret_cast<const short8*>(arow + 96);
            const float* sna = sa + i0n + 4 * h;
#pragma unroll
            for (int q = 0; q < 4; ++q) {
                f32x4 t = *reinterpret_cast<const f32x4*>(sna + 8 * q);
                cin[4 * q + 0] = t[0]; cin[4 * q + 1] = t[1];
                cin[4 * q + 2] = t[2]; cin[4 * q + 3] = t[3];
            }
            i0 = i0n;
        }
    }

    float lsum = (ls0 + ls1) + (ls2 + ls3);

    // wave reduce
#pragma unroll
    for (int off = 32; off; off >>= 1) lsum += __shfl_xor(lsum, off, 64);

    __shared__ float ws4[4];
    if (lane == 0) ws4[wid] = lsum;
    __syncthreads();
    if (tid == 0) {
        double tot = (double)ws4[0] + (double)ws4[1] + (double)ws4[2] + (double)ws4[3];
        partials[bid] = tot;
    }
}

// ---------------------------------------------------------------------------
// Finalize: reduce GRID_MAIN block partials with per-mode coefficients.
// bid < 512 -> XY (negative coeff); else sym (x2 folds sum_{i!=j}).
// ---------------------------------------------------------------------------
__global__ __launch_bounds__(256) void mmd_final(
    const double* __restrict__ partials, float* __restrict__ out)
{
    const int tid = threadIdx.x;
    const double cs = 2.0 / (8192.0 * 8191.0);       // sym modes
    const double cx = -2.0 / (8192.0 * 8192.0);      // XY

    double s = 0.0;
    for (int idx = tid; idx < GRID_MAIN; idx += 256) {
        double c = (idx < 512) ? cx : cs;
        s += partials[idx] * c;
    }
#pragma unroll
    for (int off = 32; off; off >>= 1) s += __shfl_xor(s, off, 64);

    __shared__ double wsum[4];
    const int lane = tid & 63, wid = tid >> 6;
    if (lane == 0) wsum[wid] = s;
    __syncthreads();
    if (tid == 0) {
        double mmd = wsum[0] + wsum[1] + wsum[2] + wsum[3];
        out[0] = (float)(mmd > 0.0 ? mmd : 0.0);
    }
}

// ---------------------------------------------------------------------------
extern "C" void kernel_launch(void* const* d_in, const int* in_sizes, int n_in,
                              void* d_out, int out_size, void* d_ws, size_t ws_size,
                              hipStream_t stream) {
    const float* z_seq   = (const float*)d_in[0];   // [16,512,64]
    const float* pmean   = (const float*)d_in[1];   // [64]
    const float* pstd    = (const float*)d_in[2];   // [64]
    const float* z_prior = (const float*)d_in[3];   // [8192,64]
    float* out = (float*)d_out;

    char* ws = (char*)d_ws;
    __hip_bfloat16* Xb = (__hip_bfloat16*)(ws);                    // 1 MB
    __hip_bfloat16* Yb = (__hip_bfloat16*)(ws + (1u << 20));       // 1 MB
    float* sxx = (float*)(ws + (2u << 20));                        // 32 KB
    float* syy = (float*)(ws + (2u << 20) + 32768);                // 32 KB
    double* partials = (double*)(ws + (2u << 20) + 65536);         // ~9 KB

    mmd_prep<<<dim3(1024), dim3(256), 0, stream>>>(
        z_seq, pmean, pstd, z_prior, Xb, Yb, sxx, syy);
    mmd_main<<<dim3(GRID_MAIN), dim3(256), 0, stream>>>(
        Xb, Yb, sxx, syy, partials);
    mmd_final<<<dim3(1), dim3(256), 0, stream>>>(partials, out);
}